// Round 2
// baseline (776.263 us; speedup 1.0000x reference)
//
#include <hip/hip_runtime.h>

typedef unsigned short u16;
typedef unsigned int   u32;

static __device__ __forceinline__ float bf2f(u16 u){ union{u32 i; float f;} v; v.i=(u32)u<<16; return v.f; }
static __device__ __forceinline__ u16 f2bf(float f){ union{float f; u32 i;} u; u.f=f; u32 r=u.i+0x7FFFu+((u.i>>16)&1u); return (u16)(r>>16); }

static __device__ __forceinline__ float ld1(const void* p, size_t i, int f32){
  return f32 ? ((const float*)p)[i] : bf2f(((const u16*)p)[i]);
}
static __device__ __forceinline__ float4 ld4(const void* p, size_t i, int f32){
  if (f32) return *((const float4*)((const float*)p + i));
  ushort4 v = *((const ushort4*)((const u16*)p + i));
  return make_float4(bf2f(v.x), bf2f(v.y), bf2f(v.z), bf2f(v.w));
}
static __device__ __forceinline__ void st4(void* p, size_t i, float4 v, int f32){
  if (f32) *((float4*)((float*)p + i)) = v;
  else { ushort4 o; o.x=f2bf(v.x); o.y=f2bf(v.y); o.z=f2bf(v.z); o.w=f2bf(v.w); *((ushort4*)((u16*)p + i)) = o; }
}
static __device__ __forceinline__ void st1(void* p, size_t i, float v, int f32){
  if (f32) ((float*)p)[i] = v; else ((u16*)p)[i] = f2bf(v);
}
static __device__ __forceinline__ int lde(const int* ei, size_t i, int i64){
  return i64 ? ei[2*i] : ei[i];
}
static __device__ __forceinline__ int clampi(int v, int lo, int hi){ return v<lo?lo:(v>hi?hi:v); }

// ---------------- runtime dtype detection ----------------
// flags[0]=1 if float inputs are fp32 (else packed bf16); flags[1]=1 if edge_index is int64.
__global__ void detect_kernel(const u32* __restrict__ x, const int* __restrict__ ei,
                              int* __restrict__ flags){
  __shared__ int cnt[2];
  int t = threadIdx.x;
  if (t < 2) cnt[t] = 0;
  __syncthreads();
  int good = 0;
  for (int i = t; i < 4096; i += 256){
    u32 e = (x[i] >> 7) & 0xFFu;          // exponent field of LOW u16 viewed as bf16
    if (e >= 90u && e <= 150u) good++;
  }
  atomicAdd(&cnt[0], good);
  int nzodd = 0;
  for (int i = t; i < 2048; i += 256){
    if (ei[2*i+1] != 0) nzodd++;
  }
  atomicAdd(&cnt[1], nzodd);
  __syncthreads();
  if (t == 0){
    flags[0] = (cnt[0] < 2867) ? 1 : 0;   // <70% plausible-bf16 -> fp32
    flags[1] = (cnt[1] == 0) ? 1 : 0;     // all odd u32 words zero -> int64
  }
}

// ---------------- CSR build ----------------
__global__ void count_kernel(const int* __restrict__ ei, int E, int N,
                             int* __restrict__ deg, const int* __restrict__ flags){
  int i64 = flags[1];
  int i = blockIdx.x*blockDim.x + threadIdx.x;
  int Et = E + N;
  if (i < Et){
    int d = (i < E) ? clampi(lde(ei, (size_t)E + i, i64), 0, N-1) : (i - E);
    atomicAdd(&deg[d], 1);
  }
}

__global__ __launch_bounds__(1024) void scan_kernel(const int* __restrict__ deg,
    int* __restrict__ offs, int* __restrict__ cursor, int N){
  __shared__ int part[1024];
  int t = threadIdx.x;
  int chunk = (N + 1023) >> 10;
  int lo = t * chunk, hi = min(lo + chunk, N);
  int s = 0;
  for (int i = lo; i < hi; i++) s += deg[i];
  part[t] = s; __syncthreads();
  int mine = s;
  for (int off = 1; off < 1024; off <<= 1){
    int v = (t >= off) ? part[t - off] : 0;
    __syncthreads();
    part[t] += v;
    __syncthreads();
  }
  int run = part[t] - mine;   // exclusive prefix
  for (int i = lo; i < hi; i++){ offs[i] = run; cursor[i] = run; run += deg[i]; }
  if (t == 1023) offs[N] = part[1023];
}

__global__ void scatter_kernel(const int* __restrict__ ei, int E, int N,
    int* __restrict__ cursor, int* __restrict__ csr, const int* __restrict__ flags){
  int i64 = flags[1];
  int i = blockIdx.x*blockDim.x + threadIdx.x;
  int Et = E + N;
  if (i < Et){
    int d = (i < E) ? clampi(lde(ei, (size_t)E + i, i64), 0, N-1) : (i - E);
    int p = atomicAdd(&cursor[d], 1);
    csr[p] = i;
  }
}

// ---------------- GEMM: C[M,256] = A[M,256] @ B[256,256], f32 acc, bf16 out ----------------
__global__ __launch_bounds__(256) void gemm_kernel(const void* __restrict__ A,
    const void* __restrict__ B, u16* __restrict__ C, int M, int aIsInput,
    const int* __restrict__ flags){
  int af32 = aIsInput ? flags[0] : 0;
  int bf32 = flags[0];
  __shared__ float As[16][64];   // [k][m]
  __shared__ float Bs[16][64];   // [k][n]
  int tid = threadIdx.x;
  int row0 = blockIdx.y * 64, col0 = blockIdx.x * 64;
  int tm = tid >> 4, tn = tid & 15;
  int lr = tid >> 2, lk = (tid & 3) * 4;
  int wk = tid >> 4, wn = (tid & 15) * 4;
  float acc[4][4] = {};
  for (int k0 = 0; k0 < 256; k0 += 16){
    float4 a4 = make_float4(0.f,0.f,0.f,0.f);
    if (row0 + lr < M) a4 = ld4(A, (size_t)(row0+lr)*256 + k0 + lk, af32);
    As[lk+0][lr] = a4.x; As[lk+1][lr] = a4.y;
    As[lk+2][lr] = a4.z; As[lk+3][lr] = a4.w;
    float4 b4 = ld4(B, (size_t)(k0+wk)*256 + col0 + wn, bf32);
    Bs[wk][wn+0] = b4.x; Bs[wk][wn+1] = b4.y;
    Bs[wk][wn+2] = b4.z; Bs[wk][wn+3] = b4.w;
    __syncthreads();
    #pragma unroll
    for (int k = 0; k < 16; k++){
      float4 av = *(const float4*)&As[k][tm*4];
      float4 bv = *(const float4*)&Bs[k][tn*4];
      float ar[4] = {av.x, av.y, av.z, av.w};
      float br[4] = {bv.x, bv.y, bv.z, bv.w};
      #pragma unroll
      for (int i = 0; i < 4; i++)
        #pragma unroll
        for (int j = 0; j < 4; j++)
          acc[i][j] += ar[i] * br[j];
    }
    __syncthreads();
  }
  #pragma unroll
  for (int i = 0; i < 4; i++){
    int r = row0 + tm*4 + i;
    if (r < M){
      ushort4 o;
      o.x = f2bf(acc[i][0]); o.y = f2bf(acc[i][1]);
      o.z = f2bf(acc[i][2]); o.w = f2bf(acc[i][3]);
      *(ushort4*)&C[(size_t)r*256 + col0 + tn*4] = o;
    }
  }
}

// ---------------- per-node attention scores es/ed ----------------
__global__ __launch_bounds__(256) void scores_kernel(const u16* __restrict__ h,
    const void* __restrict__ a_src, const void* __restrict__ a_dst,
    float* __restrict__ es, float* __restrict__ ed, int N, const int* __restrict__ flags){
  int f32 = flags[0];
  int n = blockIdx.x;
  int t = threadIdx.x;
  int hd = t >> 6, c = t & 63;
  float v = bf2f(h[(size_t)n*256 + t]);
  float ps = v * ld1(a_src, hd*64 + c, f32);
  float pd = v * ld1(a_dst, hd*64 + c, f32);
  #pragma unroll
  for (int off = 32; off; off >>= 1){
    ps += __shfl_down(ps, off, 64);
    pd += __shfl_down(pd, off, 64);
  }
  if (c == 0){ es[(size_t)n*4 + hd] = ps; ed[(size_t)n*4 + hd] = pd; }
}

// ---------------- per-(edge,head) weight w = exp(leaky_relu(es+ed)) ----------------
// segment-max skipped: |es+ed| <~ 10 so exp can't overflow (and clamp at 60 for safety).
__global__ void edgew_kernel(const int* __restrict__ ei, int E, int N,
    const float* __restrict__ es, const float* __restrict__ ed, float* __restrict__ w,
    const int* __restrict__ flags){
  int i64 = flags[1];
  int i = blockIdx.x*blockDim.x + threadIdx.x;
  int tot = (E + N) * 4;
  if (i >= tot) return;
  int e = i >> 2, hd = i & 3;
  int s, d;
  if (e < E){ s = clampi(lde(ei, e, i64), 0, N-1); d = clampi(lde(ei, (size_t)E + e, i64), 0, N-1); }
  else { s = e - E; d = s; }
  float x = es[(size_t)s*4 + hd] + ed[(size_t)d*4 + hd];
  x = (x > 0.f) ? x : 0.2f * x;
  x = fminf(x, 60.f);
  w[i] = __expf(x);
}

// ---------------- aggregation: one wave per dst node ----------------
__global__ __launch_bounds__(256) void agg_kernel(const u16* __restrict__ h,
    const float* __restrict__ w, const int* __restrict__ csr, const int* __restrict__ offs,
    const int* __restrict__ ei, int E, int N, const void* __restrict__ bias,
    void* __restrict__ out, int do_relu, int outIsOutput, const int* __restrict__ flags){
  int i64 = flags[1];
  int f32in = flags[0];
  int of32  = outIsOutput ? flags[0] : 0;
  int wv = threadIdx.x >> 6, ln = threadIdx.x & 63;
  int n = blockIdx.x * 4 + wv;
  if (n >= N) return;
  int beg = offs[n], end = offs[n+1];
  int hd = ln >> 4;
  float a0=0.f, a1=0.f, a2=0.f, a3=0.f, wsum=0.f;
  for (int i = beg; i < end; i++){
    int e = csr[i];
    int s = (e < E) ? clampi(lde(ei, e, i64), 0, N-1) : (e - E);
    float ww = w[(size_t)e*4 + hd];
    ushort4 hv = *(const ushort4*)&h[(size_t)s*256 + ln*4];
    a0 += ww * bf2f(hv.x); a1 += ww * bf2f(hv.y);
    a2 += ww * bf2f(hv.z); a3 += ww * bf2f(hv.w);
    wsum += ww;
  }
  float inv = 1.f / (wsum + 1e-16f);
  int c0 = ln * 4;
  float4 bv = ld4(bias, c0, f32in);
  float4 ov = make_float4(a0*inv + bv.x, a1*inv + bv.y, a2*inv + bv.z, a3*inv + bv.w);
  if (do_relu){
    ov.x = fmaxf(ov.x, 0.f); ov.y = fmaxf(ov.y, 0.f);
    ov.z = fmaxf(ov.z, 0.f); ov.w = fmaxf(ov.w, 0.f);
  }
  st4(out, (size_t)n*256 + c0, ov, of32);
}

// ---------------- query part of classifier ----------------
__global__ void qpart_kernel(const void* __restrict__ query, const void* __restrict__ Wc,
    const void* __restrict__ bc, float* __restrict__ qp, int Q, const int* __restrict__ flags){
  int f32 = flags[0];
  int q = threadIdx.x >> 5, ln = threadIdx.x & 31;
  if (q >= Q) return;
  float s = 0.f;
  for (int j = ln; j < 256; j += 32) s += ld1(query, q*256 + j, f32) * ld1(Wc, j, f32);
  #pragma unroll
  for (int off = 16; off; off >>= 1) s += __shfl_down(s, off, 32);
  if (ln == 0) qp[q] = s + ld1(bc, 0, f32);
}

// ---------------- node scores ----------------
__global__ __launch_bounds__(256) void nscore_kernel(const void* __restrict__ dout,
    const void* __restrict__ Wc, const float* __restrict__ qp, int N, int Q,
    const int* __restrict__ flags){
  int f32 = flags[0];
  int wv = threadIdx.x >> 6, ln = threadIdx.x & 63;
  int n = blockIdx.x * 4 + wv;
  if (n >= N) return;
  float4 e4 = ld4(dout, (size_t)n*256 + ln*4, f32);        // emb (already written)
  float4 w4 = ld4(Wc, 256 + ln*4, f32);
  float v = e4.x*w4.x + e4.y*w4.y + e4.z*w4.z + e4.w*w4.w;
  #pragma unroll
  for (int off = 32; off; off >>= 1) v += __shfl_down(v, off, 64);
  v = __shfl(v, 0, 64);
  if (ln < Q) st1((void*)dout, (size_t)N*256 + (size_t)ln*N + n, qp[ln] + v, f32);
}

extern "C" void kernel_launch(void* const* d_in, const int* in_sizes, int n_in,
                              void* d_out, int out_size, void* d_ws, size_t ws_size,
                              hipStream_t stream){
  const void* x     = d_in[0];
  const int*  ei    = (const int*)d_in[1];
  const void* query = d_in[2];
  const void* W1    = d_in[3];
  const void* as1   = d_in[4];
  const void* ad1   = d_in[5];
  const void* b1    = d_in[6];
  const void* W2    = d_in[7];
  const void* as2   = d_in[8];
  const void* ad2   = d_in[9];
  const void* b2    = d_in[10];
  const void* Wc    = d_in[11];
  const void* bc    = d_in[12];

  int N = in_sizes[0] / 256;
  int E = in_sizes[1] / 2;
  int Q = in_sizes[2] / 256;
  int Et = E + N;

  char* p = (char*)d_ws;
  auto alloc = [&](size_t bytes)->char*{
    char* r = p; p += (bytes + 255) & ~(size_t)255; return r;
  };
  int*  flags  = (int*) alloc(256);
  u16*  bufA   = (u16*) alloc((size_t)N*256*2);   // h1 / h2 (internal bf16)
  u16*  bufB   = (u16*) alloc((size_t)N*256*2);   // relu(agg1)+b1 = x2
  float* es    = (float*)alloc((size_t)N*4*4);
  float* ed    = (float*)alloc((size_t)N*4*4);
  float* w     = (float*)alloc((size_t)Et*4*4);
  int*  deg    = (int*)  alloc((size_t)N*4);
  int*  offs   = (int*)  alloc((size_t)(N+1)*4);
  int*  cursor = (int*)  alloc((size_t)N*4);
  int*  csr    = (int*)  alloc((size_t)Et*4);
  float* qp    = (float*)alloc(64*4);

  const int thr = 256;
  detect_kernel<<<1, 256, 0, stream>>>((const u32*)x, ei, flags);

  hipMemsetAsync(deg, 0, (size_t)N*4, stream);
  count_kernel  <<<(Et + thr-1)/thr, thr, 0, stream>>>(ei, E, N, deg, flags);
  scan_kernel   <<<1, 1024, 0, stream>>>(deg, offs, cursor, N);
  scatter_kernel<<<(Et + thr-1)/thr, thr, 0, stream>>>(ei, E, N, cursor, csr, flags);

  dim3 ggrid(4, (N + 63)/64);
  // ---- layer 1 ----
  gemm_kernel  <<<ggrid, 256, 0, stream>>>(x, W1, bufA, N, 1, flags);
  scores_kernel<<<N, 256, 0, stream>>>(bufA, as1, ad1, es, ed, N, flags);
  edgew_kernel <<<(Et*4 + thr-1)/thr, thr, 0, stream>>>(ei, E, N, es, ed, w, flags);
  agg_kernel   <<<(N + 3)/4, 256, 0, stream>>>(bufA, w, csr, offs, ei, E, N, b1, bufB, 1, 0, flags);
  // ---- layer 2 ----
  gemm_kernel  <<<ggrid, 256, 0, stream>>>(bufB, W2, bufA, N, 0, flags);
  scores_kernel<<<N, 256, 0, stream>>>(bufA, as2, ad2, es, ed, N, flags);
  edgew_kernel <<<(Et*4 + thr-1)/thr, thr, 0, stream>>>(ei, E, N, es, ed, w, flags);
  agg_kernel   <<<(N + 3)/4, 256, 0, stream>>>(bufA, w, csr, offs, ei, E, N, b2, d_out, 0, 1, flags);
  // ---- classifier head ----
  qpart_kernel <<<1, 256, 0, stream>>>(query, Wc, bc, qp, Q, flags);
  nscore_kernel<<<(N + 3)/4, 256, 0, stream>>>(d_out, Wc, qp, N, Q, flags);
}

// Round 3
// 453.177 us; speedup vs baseline: 1.7129x; 1.7129x over previous
//
#include <hip/hip_runtime.h>

typedef unsigned short u16;
typedef unsigned int   u32;
typedef __attribute__((ext_vector_type(8))) short short8v;
typedef __attribute__((ext_vector_type(8))) unsigned short us8;
typedef __attribute__((ext_vector_type(4))) float f32x4;

static __device__ __forceinline__ float bf2f(u16 u){ union{u32 i; float f;} v; v.i=(u32)u<<16; return v.f; }
static __device__ __forceinline__ u16 f2bf(float f){ union{float f; u32 i;} u; u.f=f; u32 r=u.i+0x7FFFu+((u.i>>16)&1u); return (u16)(r>>16); }

static __device__ __forceinline__ float ld1(const void* p, size_t i, int f32){
  return f32 ? ((const float*)p)[i] : bf2f(((const u16*)p)[i]);
}
static __device__ __forceinline__ float4 ld4(const void* p, size_t i, int f32){
  if (f32) return *((const float4*)((const float*)p + i));
  ushort4 v = *((const ushort4*)((const u16*)p + i));
  return make_float4(bf2f(v.x), bf2f(v.y), bf2f(v.z), bf2f(v.w));
}
static __device__ __forceinline__ void st4(void* p, size_t i, float4 v, int f32){
  if (f32) *((float4*)((float*)p + i)) = v;
  else { ushort4 o; o.x=f2bf(v.x); o.y=f2bf(v.y); o.z=f2bf(v.z); o.w=f2bf(v.w); *((ushort4*)((u16*)p + i)) = o; }
}
static __device__ __forceinline__ void st1(void* p, size_t i, float v, int f32){
  if (f32) ((float*)p)[i] = v; else ((u16*)p)[i] = f2bf(v);
}
static __device__ __forceinline__ int lde(const int* ei, size_t i, int i64){
  return i64 ? ei[2*i] : ei[i];
}
static __device__ __forceinline__ int clampi(int v, int lo, int hi){ return v<lo?lo:(v>hi?hi:v); }

// ---------------- runtime dtype detection ----------------
__global__ void detect_kernel(const u32* __restrict__ x, const int* __restrict__ ei,
                              int* __restrict__ flags){
  __shared__ int cnt[2];
  int t = threadIdx.x;
  if (t < 2) cnt[t] = 0;
  __syncthreads();
  int good = 0;
  for (int i = t; i < 4096; i += 256){
    u32 e = (x[i] >> 7) & 0xFFu;
    if (e >= 90u && e <= 150u) good++;
  }
  atomicAdd(&cnt[0], good);
  int nzodd = 0;
  for (int i = t; i < 2048; i += 256){
    if (ei[2*i+1] != 0) nzodd++;
  }
  atomicAdd(&cnt[1], nzodd);
  __syncthreads();
  if (t == 0){
    flags[0] = (cnt[0] < 2867) ? 1 : 0;
    flags[1] = (cnt[1] == 0) ? 1 : 0;
  }
}

// ---------------- CSR build (stores SRC node id directly) ----------------
__global__ void count_kernel(const int* __restrict__ ei, int E, int N,
                             int* __restrict__ deg, const int* __restrict__ flags){
  int i64 = flags[1];
  int i = blockIdx.x*blockDim.x + threadIdx.x;
  int Et = E + N;
  if (i < Et){
    int d = (i < E) ? clampi(lde(ei, (size_t)E + i, i64), 0, N-1) : (i - E);
    atomicAdd(&deg[d], 1);
  }
}

__global__ __launch_bounds__(1024) void scan_kernel(const int* __restrict__ deg,
    int* __restrict__ offs, int* __restrict__ cursor, int N){
  __shared__ int part[1024];
  int t = threadIdx.x;
  int chunk = (N + 1023) >> 10;
  int lo = t * chunk, hi = min(lo + chunk, N);
  int s = 0;
  for (int i = lo; i < hi; i++) s += deg[i];
  part[t] = s; __syncthreads();
  int mine = s;
  for (int off = 1; off < 1024; off <<= 1){
    int v = (t >= off) ? part[t - off] : 0;
    __syncthreads();
    part[t] += v;
    __syncthreads();
  }
  int run = part[t] - mine;
  for (int i = lo; i < hi; i++){ offs[i] = run; cursor[i] = run; run += deg[i]; }
  if (t == 1023) offs[N] = part[1023];
}

__global__ void scatter_kernel(const int* __restrict__ ei, int E, int N,
    int* __restrict__ cursor, int* __restrict__ csr_src, const int* __restrict__ flags){
  int i64 = flags[1];
  int i = blockIdx.x*blockDim.x + threadIdx.x;
  int Et = E + N;
  if (i < Et){
    int s, d;
    if (i < E){
      s = clampi(lde(ei, i, i64), 0, N-1);
      d = clampi(lde(ei, (size_t)E + i, i64), 0, N-1);
    } else { s = i - E; d = s; }
    int p = atomicAdd(&cursor[d], 1);
    csr_src[p] = s;
  }
}

// ---------------- MFMA GEMM: C[M,256] = A[M,256] @ B[256,256], bf16 mfma, f32 acc ----------------
// Block: 256 thr (4 waves, 2x2), tile 128 rows x 64 cols. B-panel staged once (transposed).
__global__ __launch_bounds__(256) void gemm_mfma(const void* __restrict__ A,
    const void* __restrict__ B, u16* __restrict__ C, int M, int aIsInput,
    const int* __restrict__ flags){
  int af32 = aIsInput ? flags[0] : 0;
  int bf32 = flags[0];
  __shared__ __align__(16) u16 As[128][40];    // 32-K step, stride 40 (80B: aligned, ~2-way max)
  __shared__ __align__(16) u16 Bt[64][264];    // [col][k], stride 264 (528B: aligned, 2-way free)
  int tid = threadIdx.x;
  int col0 = blockIdx.x * 64;
  int row0 = blockIdx.y * 128;

  { // stage whole B-panel transposed: thread t = row k of B
    int k = tid;
    if (bf32){
      const float* Bp = (const float*)B + (size_t)k*256 + col0;
      #pragma unroll
      for (int j = 0; j < 64; j += 4){
        float4 v = *(const float4*)(Bp + j);
        Bt[j+0][k] = f2bf(v.x); Bt[j+1][k] = f2bf(v.y);
        Bt[j+2][k] = f2bf(v.z); Bt[j+3][k] = f2bf(v.w);
      }
    } else {
      const u16* Bp = (const u16*)B + (size_t)k*256 + col0;
      #pragma unroll
      for (int j = 0; j < 64; j += 4){
        ushort4 v = *(const ushort4*)(Bp + j);
        Bt[j+0][k] = v.x; Bt[j+1][k] = v.y; Bt[j+2][k] = v.z; Bt[j+3][k] = v.w;
      }
    }
  }

  int wave = tid >> 6, lane = tid & 63;
  int wm = wave >> 1, wn = wave & 1;
  int l15 = lane & 15, l4 = lane >> 4;
  f32x4 acc[4][2] = {};
  int arow = tid >> 1, akseg = (tid & 1) * 16;

  for (int k0 = 0; k0 < 256; k0 += 32){
    __syncthreads();   // prev reads done (first iter: B staging done)
    { // stage A rows [row0, row0+128) x [k0, k0+32)
      int gr = row0 + arow;
      us8 p0 = (us8){0,0,0,0,0,0,0,0}, p1 = (us8){0,0,0,0,0,0,0,0};
      if (gr < M){
        if (af32){
          const float* Ap = (const float*)A + (size_t)gr*256 + k0 + akseg;
          float4 a0 = *(const float4*)(Ap+0), a1 = *(const float4*)(Ap+4);
          float4 a2 = *(const float4*)(Ap+8), a3 = *(const float4*)(Ap+12);
          p0 = (us8){f2bf(a0.x),f2bf(a0.y),f2bf(a0.z),f2bf(a0.w),
                     f2bf(a1.x),f2bf(a1.y),f2bf(a1.z),f2bf(a1.w)};
          p1 = (us8){f2bf(a2.x),f2bf(a2.y),f2bf(a2.z),f2bf(a2.w),
                     f2bf(a3.x),f2bf(a3.y),f2bf(a3.z),f2bf(a3.w)};
        } else {
          const u16* Ap = (const u16*)A + (size_t)gr*256 + k0 + akseg;
          p0 = *(const us8*)Ap; p1 = *(const us8*)(Ap+8);
        }
      }
      *(us8*)&As[arow][akseg]   = p0;
      *(us8*)&As[arow][akseg+8] = p1;
    }
    __syncthreads();
    short8v a[4], b[2];
    #pragma unroll
    for (int mi = 0; mi < 4; mi++)
      a[mi] = *(const short8v*)&As[wm*64 + mi*16 + l15][8*l4];
    #pragma unroll
    for (int ni = 0; ni < 2; ni++)
      b[ni] = *(const short8v*)&Bt[wn*32 + ni*16 + l15][k0 + 8*l4];
    #pragma unroll
    for (int mi = 0; mi < 4; mi++)
      #pragma unroll
      for (int ni = 0; ni < 2; ni++)
        acc[mi][ni] = __builtin_amdgcn_mfma_f32_16x16x32_bf16(a[mi], b[ni], acc[mi][ni], 0, 0, 0);
  }

  #pragma unroll
  for (int mi = 0; mi < 4; mi++){
    #pragma unroll
    for (int ni = 0; ni < 2; ni++){
      #pragma unroll
      for (int r = 0; r < 4; r++){
        int row = row0 + wm*64 + mi*16 + l4*4 + r;
        int col = col0 + wn*32 + ni*16 + l15;
        if (row < M) C[(size_t)row*256 + col] = f2bf(acc[mi][ni][r]);
      }
    }
  }
}

// ---------------- per-node attention scores es/ed (4 nodes/block) ----------------
__global__ __launch_bounds__(256) void scores_kernel(const u16* __restrict__ h,
    const void* __restrict__ a_src, const void* __restrict__ a_dst,
    float* __restrict__ es, float* __restrict__ ed, int N, const int* __restrict__ flags){
  int f32 = flags[0];
  int ln = threadIdx.x & 63;
  int n = blockIdx.x*4 + (threadIdx.x >> 6);
  if (n >= N) return;
  int c0 = ln*4, hd = ln >> 4;
  ushort4 hv = *(const ushort4*)&h[(size_t)n*256 + c0];
  float4 s4 = ld4(a_src, c0, f32);
  float4 d4 = ld4(a_dst, c0, f32);
  float ps = bf2f(hv.x)*s4.x + bf2f(hv.y)*s4.y + bf2f(hv.z)*s4.z + bf2f(hv.w)*s4.w;
  float pd = bf2f(hv.x)*d4.x + bf2f(hv.y)*d4.y + bf2f(hv.z)*d4.z + bf2f(hv.w)*d4.w;
  #pragma unroll
  for (int off = 1; off < 16; off <<= 1){
    ps += __shfl_xor(ps, off, 64);
    pd += __shfl_xor(pd, off, 64);
  }
  if ((ln & 15) == 0){ es[(size_t)n*4 + hd] = ps; ed[(size_t)n*4 + hd] = pd; }
}

// ---------------- fused aggregation: wave per dst, weight computed inline ----------------
__global__ __launch_bounds__(256) void agg_kernel(const u16* __restrict__ h,
    const int* __restrict__ csr_src, const int* __restrict__ offs,
    const float* __restrict__ es, const float* __restrict__ ed, int N,
    const void* __restrict__ bias, void* __restrict__ out, int do_relu, int outIsOutput,
    const int* __restrict__ flags){
  int f32in = flags[0];
  int of32  = outIsOutput ? flags[0] : 0;
  int ln = threadIdx.x & 63;
  int n = blockIdx.x*4 + (threadIdx.x >> 6);
  if (n >= N) return;
  int beg = offs[n], end = offs[n+1];
  int hd = ln >> 4, c0 = ln*4;
  float edn = ed[(size_t)n*4 + hd];
  float a0=0.f, a1=0.f, a2=0.f, a3=0.f, ws=0.f;
  int i = beg;
  for (; i + 8 <= end; i += 8){
    int s[8]; float x[8]; ushort4 hv[8];
    #pragma unroll
    for (int j = 0; j < 8; j++) s[j] = csr_src[i+j];
    #pragma unroll
    for (int j = 0; j < 8; j++) x[j] = es[(size_t)s[j]*4 + hd];
    #pragma unroll
    for (int j = 0; j < 8; j++) hv[j] = *(const ushort4*)&h[(size_t)s[j]*256 + c0];
    #pragma unroll
    for (int j = 0; j < 8; j++){
      float t = x[j] + edn; t = (t > 0.f) ? t : 0.2f*t; t = fminf(t, 60.f);
      float w = __expf(t);
      a0 += w*bf2f(hv[j].x); a1 += w*bf2f(hv[j].y);
      a2 += w*bf2f(hv[j].z); a3 += w*bf2f(hv[j].w);
      ws += w;
    }
  }
  for (; i + 4 <= end; i += 4){
    int s[4]; float x[4]; ushort4 hv[4];
    #pragma unroll
    for (int j = 0; j < 4; j++) s[j] = csr_src[i+j];
    #pragma unroll
    for (int j = 0; j < 4; j++) x[j] = es[(size_t)s[j]*4 + hd];
    #pragma unroll
    for (int j = 0; j < 4; j++) hv[j] = *(const ushort4*)&h[(size_t)s[j]*256 + c0];
    #pragma unroll
    for (int j = 0; j < 4; j++){
      float t = x[j] + edn; t = (t > 0.f) ? t : 0.2f*t; t = fminf(t, 60.f);
      float w = __expf(t);
      a0 += w*bf2f(hv[j].x); a1 += w*bf2f(hv[j].y);
      a2 += w*bf2f(hv[j].z); a3 += w*bf2f(hv[j].w);
      ws += w;
    }
  }
  for (; i < end; i++){
    int s = csr_src[i];
    float t = es[(size_t)s*4 + hd] + edn; t = (t > 0.f) ? t : 0.2f*t; t = fminf(t, 60.f);
    float w = __expf(t);
    ushort4 hv = *(const ushort4*)&h[(size_t)s*256 + c0];
    a0 += w*bf2f(hv.x); a1 += w*bf2f(hv.y);
    a2 += w*bf2f(hv.z); a3 += w*bf2f(hv.w);
    ws += w;
  }
  float inv = 1.f / (ws + 1e-16f);
  float4 bv = ld4(bias, c0, f32in);
  float4 ov = make_float4(a0*inv + bv.x, a1*inv + bv.y, a2*inv + bv.z, a3*inv + bv.w);
  if (do_relu){
    ov.x = fmaxf(ov.x, 0.f); ov.y = fmaxf(ov.y, 0.f);
    ov.z = fmaxf(ov.z, 0.f); ov.w = fmaxf(ov.w, 0.f);
  }
  st4(out, (size_t)n*256 + c0, ov, of32);
}

// ---------------- query part of classifier ----------------
__global__ void qpart_kernel(const void* __restrict__ query, const void* __restrict__ Wc,
    const void* __restrict__ bc, float* __restrict__ qp, int Q, const int* __restrict__ flags){
  int f32 = flags[0];
  int q = threadIdx.x >> 5, ln = threadIdx.x & 31;
  if (q >= Q) return;
  float s = 0.f;
  for (int j = ln; j < 256; j += 32) s += ld1(query, q*256 + j, f32) * ld1(Wc, j, f32);
  #pragma unroll
  for (int off = 16; off; off >>= 1) s += __shfl_down(s, off, 32);
  if (ln == 0) qp[q] = s + ld1(bc, 0, f32);
}

// ---------------- node scores ----------------
__global__ __launch_bounds__(256) void nscore_kernel(const void* __restrict__ dout,
    const void* __restrict__ Wc, const float* __restrict__ qp, int N, int Q,
    const int* __restrict__ flags){
  int f32 = flags[0];
  int wv = threadIdx.x >> 6, ln = threadIdx.x & 63;
  int n = blockIdx.x * 4 + wv;
  if (n >= N) return;
  float4 e4 = ld4(dout, (size_t)n*256 + ln*4, f32);
  float4 w4 = ld4(Wc, 256 + ln*4, f32);
  float v = e4.x*w4.x + e4.y*w4.y + e4.z*w4.z + e4.w*w4.w;
  #pragma unroll
  for (int off = 32; off; off >>= 1) v += __shfl_down(v, off, 64);
  v = __shfl(v, 0, 64);
  if (ln < Q) st1((void*)dout, (size_t)N*256 + (size_t)ln*N + n, qp[ln] + v, f32);
}

extern "C" void kernel_launch(void* const* d_in, const int* in_sizes, int n_in,
                              void* d_out, int out_size, void* d_ws, size_t ws_size,
                              hipStream_t stream){
  const void* x     = d_in[0];
  const int*  ei    = (const int*)d_in[1];
  const void* query = d_in[2];
  const void* W1    = d_in[3];
  const void* as1   = d_in[4];
  const void* ad1   = d_in[5];
  const void* b1    = d_in[6];
  const void* W2    = d_in[7];
  const void* as2   = d_in[8];
  const void* ad2   = d_in[9];
  const void* b2    = d_in[10];
  const void* Wc    = d_in[11];
  const void* bc    = d_in[12];

  int N = in_sizes[0] / 256;
  int E = in_sizes[1] / 2;
  int Q = in_sizes[2] / 256;
  int Et = E + N;

  char* p = (char*)d_ws;
  auto alloc = [&](size_t bytes)->char*{
    char* r = p; p += (bytes + 255) & ~(size_t)255; return r;
  };
  int*  flags   = (int*) alloc(256);
  u16*  bufA    = (u16*) alloc((size_t)N*256*2);
  u16*  bufB    = (u16*) alloc((size_t)N*256*2);
  float* es     = (float*)alloc((size_t)N*4*4);
  float* ed     = (float*)alloc((size_t)N*4*4);
  int*  deg     = (int*)  alloc((size_t)N*4);
  int*  offs    = (int*)  alloc((size_t)(N+1)*4);
  int*  cursor  = (int*)  alloc((size_t)N*4);
  int*  csr_src = (int*)  alloc((size_t)Et*4);
  float* qp     = (float*)alloc(64*4);

  const int thr = 256;
  detect_kernel<<<1, 256, 0, stream>>>((const u32*)x, ei, flags);

  hipMemsetAsync(deg, 0, (size_t)N*4, stream);
  count_kernel  <<<(Et + thr-1)/thr, thr, 0, stream>>>(ei, E, N, deg, flags);
  scan_kernel   <<<1, 1024, 0, stream>>>(deg, offs, cursor, N);
  scatter_kernel<<<(Et + thr-1)/thr, thr, 0, stream>>>(ei, E, N, cursor, csr_src, flags);

  dim3 ggrid(4, (N + 127)/128);
  dim3 ngrid((N + 3)/4);
  // ---- layer 1 ----
  gemm_mfma    <<<ggrid, 256, 0, stream>>>(x, W1, bufA, N, 1, flags);
  scores_kernel<<<ngrid, 256, 0, stream>>>(bufA, as1, ad1, es, ed, N, flags);
  agg_kernel   <<<ngrid, 256, 0, stream>>>(bufA, csr_src, offs, es, ed, N, b1, bufB, 1, 0, flags);
  // ---- layer 2 ----
  gemm_mfma    <<<ggrid, 256, 0, stream>>>(bufB, W2, bufA, N, 0, flags);
  scores_kernel<<<ngrid, 256, 0, stream>>>(bufA, as2, ad2, es, ed, N, flags);
  agg_kernel   <<<ngrid, 256, 0, stream>>>(bufA, csr_src, offs, es, ed, N, b2, d_out, 0, 1, flags);
  // ---- classifier head ----
  qpart_kernel <<<1, 256, 0, stream>>>(query, Wc, bc, qp, Q, flags);
  nscore_kernel<<<ngrid, 256, 0, stream>>>(d_out, Wc, qp, N, Q, flags);
}

// Round 4
// 355.983 us; speedup vs baseline: 2.1806x; 1.2730x over previous
//
#include <hip/hip_runtime.h>

typedef unsigned short u16;
typedef unsigned int   u32;
typedef __attribute__((ext_vector_type(8))) short short8v;
typedef __attribute__((ext_vector_type(8))) unsigned short us8;
typedef __attribute__((ext_vector_type(4))) float f32x4;

static __device__ __forceinline__ float bf2f(u16 u){ union{u32 i; float f;} v; v.i=(u32)u<<16; return v.f; }
static __device__ __forceinline__ u16 f2bf(float f){ union{float f; u32 i;} u; u.f=f; u32 r=u.i+0x7FFFu+((u.i>>16)&1u); return (u16)(r>>16); }

static __device__ __forceinline__ float ld1(const void* p, size_t i, int f32){
  return f32 ? ((const float*)p)[i] : bf2f(((const u16*)p)[i]);
}
static __device__ __forceinline__ float4 ld4(const void* p, size_t i, int f32){
  if (f32) return *((const float4*)((const float*)p + i));
  ushort4 v = *((const ushort4*)((const u16*)p + i));
  return make_float4(bf2f(v.x), bf2f(v.y), bf2f(v.z), bf2f(v.w));
}
static __device__ __forceinline__ void st4(void* p, size_t i, float4 v, int f32){
  if (f32) *((float4*)((float*)p + i)) = v;
  else { ushort4 o; o.x=f2bf(v.x); o.y=f2bf(v.y); o.z=f2bf(v.z); o.w=f2bf(v.w); *((ushort4*)((u16*)p + i)) = o; }
}
static __device__ __forceinline__ void st1(void* p, size_t i, float v, int f32){
  if (f32) ((float*)p)[i] = v; else ((u16*)p)[i] = f2bf(v);
}
static __device__ __forceinline__ int lde(const int* ei, size_t i, int i64){
  return i64 ? ei[2*i] : ei[i];
}
static __device__ __forceinline__ int clampi(int v, int lo, int hi){ return v<lo?lo:(v>hi?hi:v); }

// ---------------- runtime dtype detection ----------------
__global__ void detect_kernel(const u32* __restrict__ x, const int* __restrict__ ei,
                              int* __restrict__ flags){
  __shared__ int cnt[2];
  int t = threadIdx.x;
  if (t < 2) cnt[t] = 0;
  __syncthreads();
  int good = 0;
  for (int i = t; i < 4096; i += 256){
    u32 e = (x[i] >> 7) & 0xFFu;
    if (e >= 90u && e <= 150u) good++;
  }
  atomicAdd(&cnt[0], good);
  int nzodd = 0;
  for (int i = t; i < 2048; i += 256){
    if (ei[2*i+1] != 0) nzodd++;
  }
  atomicAdd(&cnt[1], nzodd);
  __syncthreads();
  if (t == 0){
    flags[0] = (cnt[0] < 2867) ? 1 : 0;
    flags[1] = (cnt[1] == 0) ? 1 : 0;
  }
}

// ---------------- CSR build (stores SRC node id directly) ----------------
__global__ void count_kernel(const int* __restrict__ ei, int E, int N,
                             int* __restrict__ deg, const int* __restrict__ flags){
  int i64 = flags[1];
  int i = blockIdx.x*blockDim.x + threadIdx.x;
  int Et = E + N;
  if (i < Et){
    int d = (i < E) ? clampi(lde(ei, (size_t)E + i, i64), 0, N-1) : (i - E);
    atomicAdd(&deg[d], 1);
  }
}

// ---- 3-stage grid scan: deg -> offs (exclusive) + cursor; offs[N]=total ----
__global__ __launch_bounds__(256) void scan1_kernel(const int* __restrict__ deg,
    int* __restrict__ offs, int* __restrict__ bsum, int N){
  __shared__ int sm[256];
  int t = threadIdx.x;
  int i = blockIdx.x*256 + t;
  int v = (i < N) ? deg[i] : 0;
  sm[t] = v; __syncthreads();
  #pragma unroll
  for (int off = 1; off < 256; off <<= 1){
    int u = (t >= off) ? sm[t-off] : 0;
    __syncthreads();
    sm[t] += u;
    __syncthreads();
  }
  if (i < N) offs[i] = sm[t] - v;          // local exclusive prefix
  if (t == 255) bsum[blockIdx.x] = sm[255];
}

__global__ __launch_bounds__(1024) void scan2_kernel(const int* __restrict__ bsum,
    int* __restrict__ bpre, int NB){
  __shared__ int sm[1024];
  int t = threadIdx.x;
  int v = (t < NB) ? bsum[t] : 0;
  sm[t] = v; __syncthreads();
  #pragma unroll
  for (int off = 1; off < 1024; off <<= 1){
    int u = (t >= off) ? sm[t-off] : 0;
    __syncthreads();
    sm[t] += u;
    __syncthreads();
  }
  if (t < NB) bpre[t] = sm[t] - v;         // exclusive over block totals
  if (t == 1023) bpre[NB] = sm[1023];      // grand total
}

__global__ __launch_bounds__(256) void scan3_kernel(int* __restrict__ offs,
    int* __restrict__ cursor, const int* __restrict__ bpre, int N, int NB){
  int i = blockIdx.x*256 + threadIdx.x;
  if (i < N){
    int v = offs[i] + bpre[blockIdx.x];
    offs[i] = v; cursor[i] = v;
  }
  if (i == 0) offs[N] = bpre[NB];
}

__global__ void scatter_kernel(const int* __restrict__ ei, int E, int N,
    int* __restrict__ cursor, int* __restrict__ csr_src, const int* __restrict__ flags){
  int i64 = flags[1];
  int i = blockIdx.x*blockDim.x + threadIdx.x;
  int Et = E + N;
  if (i < Et){
    int s, d;
    if (i < E){
      s = clampi(lde(ei, i, i64), 0, N-1);
      d = clampi(lde(ei, (size_t)E + i, i64), 0, N-1);
    } else { s = i - E; d = s; }
    int p = atomicAdd(&cursor[d], 1);
    csr_src[p] = s;
  }
}

// ---------------- MFMA GEMM: C[M,256] = A[M,256] @ B[256,256], bf16 mfma, f32 acc ----------------
__global__ __launch_bounds__(256) void gemm_mfma(const void* __restrict__ A,
    const void* __restrict__ B, u16* __restrict__ C, int M, int aIsInput,
    const int* __restrict__ flags){
  int af32 = aIsInput ? flags[0] : 0;
  int bf32 = flags[0];
  __shared__ __align__(16) u16 As[128][40];
  __shared__ __align__(16) u16 Bt[64][264];
  int tid = threadIdx.x;
  int col0 = blockIdx.x * 64;
  int row0 = blockIdx.y * 128;

  { // stage whole B-panel transposed: thread t = row k of B
    int k = tid;
    if (bf32){
      const float* Bp = (const float*)B + (size_t)k*256 + col0;
      #pragma unroll
      for (int j = 0; j < 64; j += 4){
        float4 v = *(const float4*)(Bp + j);
        Bt[j+0][k] = f2bf(v.x); Bt[j+1][k] = f2bf(v.y);
        Bt[j+2][k] = f2bf(v.z); Bt[j+3][k] = f2bf(v.w);
      }
    } else {
      const u16* Bp = (const u16*)B + (size_t)k*256 + col0;
      #pragma unroll
      for (int j = 0; j < 64; j += 4){
        ushort4 v = *(const ushort4*)(Bp + j);
        Bt[j+0][k] = v.x; Bt[j+1][k] = v.y; Bt[j+2][k] = v.z; Bt[j+3][k] = v.w;
      }
    }
  }

  int wave = tid >> 6, lane = tid & 63;
  int wm = wave >> 1, wn = wave & 1;
  int l15 = lane & 15, l4 = lane >> 4;
  f32x4 acc[4][2] = {};
  int arow = tid >> 1, akseg = (tid & 1) * 16;

  for (int k0 = 0; k0 < 256; k0 += 32){
    __syncthreads();
    { // stage A rows [row0, row0+128) x [k0, k0+32)
      int gr = row0 + arow;
      us8 p0 = (us8){0,0,0,0,0,0,0,0}, p1 = (us8){0,0,0,0,0,0,0,0};
      if (gr < M){
        if (af32){
          const float* Ap = (const float*)A + (size_t)gr*256 + k0 + akseg;
          float4 a0 = *(const float4*)(Ap+0), a1 = *(const float4*)(Ap+4);
          float4 a2 = *(const float4*)(Ap+8), a3 = *(const float4*)(Ap+12);
          p0 = (us8){f2bf(a0.x),f2bf(a0.y),f2bf(a0.z),f2bf(a0.w),
                     f2bf(a1.x),f2bf(a1.y),f2bf(a1.z),f2bf(a1.w)};
          p1 = (us8){f2bf(a2.x),f2bf(a2.y),f2bf(a2.z),f2bf(a2.w),
                     f2bf(a3.x),f2bf(a3.y),f2bf(a3.z),f2bf(a3.w)};
        } else {
          const u16* Ap = (const u16*)A + (size_t)gr*256 + k0 + akseg;
          p0 = *(const us8*)Ap; p1 = *(const us8*)(Ap+8);
        }
      }
      *(us8*)&As[arow][akseg]   = p0;
      *(us8*)&As[arow][akseg+8] = p1;
    }
    __syncthreads();
    short8v a[4], b[2];
    #pragma unroll
    for (int mi = 0; mi < 4; mi++)
      a[mi] = *(const short8v*)&As[wm*64 + mi*16 + l15][8*l4];
    #pragma unroll
    for (int ni = 0; ni < 2; ni++)
      b[ni] = *(const short8v*)&Bt[wn*32 + ni*16 + l15][k0 + 8*l4];
    #pragma unroll
    for (int mi = 0; mi < 4; mi++)
      #pragma unroll
      for (int ni = 0; ni < 2; ni++)
        acc[mi][ni] = __builtin_amdgcn_mfma_f32_16x16x32_bf16(a[mi], b[ni], acc[mi][ni], 0, 0, 0);
  }

  #pragma unroll
  for (int mi = 0; mi < 4; mi++){
    #pragma unroll
    for (int ni = 0; ni < 2; ni++){
      #pragma unroll
      for (int r = 0; r < 4; r++){
        int row = row0 + wm*64 + mi*16 + l4*4 + r;
        int col = col0 + wn*32 + ni*16 + l15;
        if (row < M) C[(size_t)row*256 + col] = f2bf(acc[mi][ni][r]);
      }
    }
  }
}

// ---------------- per-node attention scores es/ed (4 nodes/block) ----------------
__global__ __launch_bounds__(256) void scores_kernel(const u16* __restrict__ h,
    const void* __restrict__ a_src, const void* __restrict__ a_dst,
    float* __restrict__ es, float* __restrict__ ed, int N, const int* __restrict__ flags){
  int f32 = flags[0];
  int ln = threadIdx.x & 63;
  int n = blockIdx.x*4 + (threadIdx.x >> 6);
  if (n >= N) return;
  int c0 = ln*4, hd = ln >> 4;
  ushort4 hv = *(const ushort4*)&h[(size_t)n*256 + c0];
  float4 s4 = ld4(a_src, c0, f32);
  float4 d4 = ld4(a_dst, c0, f32);
  float ps = bf2f(hv.x)*s4.x + bf2f(hv.y)*s4.y + bf2f(hv.z)*s4.z + bf2f(hv.w)*s4.w;
  float pd = bf2f(hv.x)*d4.x + bf2f(hv.y)*d4.y + bf2f(hv.z)*d4.z + bf2f(hv.w)*d4.w;
  #pragma unroll
  for (int off = 1; off < 16; off <<= 1){
    ps += __shfl_xor(ps, off, 64);
    pd += __shfl_xor(pd, off, 64);
  }
  if ((ln & 15) == 0){ es[(size_t)n*4 + hd] = ps; ed[(size_t)n*4 + hd] = pd; }
}

// ---------------- fused aggregation: wave per dst, weight computed inline ----------------
__global__ __launch_bounds__(256) void agg_kernel(const u16* __restrict__ h,
    const int* __restrict__ csr_src, const int* __restrict__ offs,
    const float* __restrict__ es, const float* __restrict__ ed, int N,
    const void* __restrict__ bias, void* __restrict__ out, int do_relu, int outIsOutput,
    const int* __restrict__ flags){
  int f32in = flags[0];
  int of32  = outIsOutput ? flags[0] : 0;
  int ln = threadIdx.x & 63;
  int n = blockIdx.x*4 + (threadIdx.x >> 6);
  if (n >= N) return;
  int beg = offs[n], end = offs[n+1];
  int hd = ln >> 4, c0 = ln*4;
  float edn = ed[(size_t)n*4 + hd];
  float a0=0.f, a1=0.f, a2=0.f, a3=0.f, ws=0.f;
  int i = beg;
  for (; i + 8 <= end; i += 8){
    int s[8]; float x[8]; ushort4 hv[8];
    #pragma unroll
    for (int j = 0; j < 8; j++) s[j] = csr_src[i+j];
    #pragma unroll
    for (int j = 0; j < 8; j++) x[j] = es[(size_t)s[j]*4 + hd];
    #pragma unroll
    for (int j = 0; j < 8; j++) hv[j] = *(const ushort4*)&h[(size_t)s[j]*256 + c0];
    #pragma unroll
    for (int j = 0; j < 8; j++){
      float t = x[j] + edn; t = (t > 0.f) ? t : 0.2f*t; t = fminf(t, 60.f);
      float w = __expf(t);
      a0 += w*bf2f(hv[j].x); a1 += w*bf2f(hv[j].y);
      a2 += w*bf2f(hv[j].z); a3 += w*bf2f(hv[j].w);
      ws += w;
    }
  }
  for (; i + 4 <= end; i += 4){
    int s[4]; float x[4]; ushort4 hv[4];
    #pragma unroll
    for (int j = 0; j < 4; j++) s[j] = csr_src[i+j];
    #pragma unroll
    for (int j = 0; j < 4; j++) x[j] = es[(size_t)s[j]*4 + hd];
    #pragma unroll
    for (int j = 0; j < 4; j++) hv[j] = *(const ushort4*)&h[(size_t)s[j]*256 + c0];
    #pragma unroll
    for (int j = 0; j < 4; j++){
      float t = x[j] + edn; t = (t > 0.f) ? t : 0.2f*t; t = fminf(t, 60.f);
      float w = __expf(t);
      a0 += w*bf2f(hv[j].x); a1 += w*bf2f(hv[j].y);
      a2 += w*bf2f(hv[j].z); a3 += w*bf2f(hv[j].w);
      ws += w;
    }
  }
  for (; i < end; i++){
    int s = csr_src[i];
    float t = es[(size_t)s*4 + hd] + edn; t = (t > 0.f) ? t : 0.2f*t; t = fminf(t, 60.f);
    float w = __expf(t);
    ushort4 hv = *(const ushort4*)&h[(size_t)s*256 + c0];
    a0 += w*bf2f(hv.x); a1 += w*bf2f(hv.y);
    a2 += w*bf2f(hv.z); a3 += w*bf2f(hv.w);
    ws += w;
  }
  float inv = 1.f / (ws + 1e-16f);
  float4 bv = ld4(bias, c0, f32in);
  float4 ov = make_float4(a0*inv + bv.x, a1*inv + bv.y, a2*inv + bv.z, a3*inv + bv.w);
  if (do_relu){
    ov.x = fmaxf(ov.x, 0.f); ov.y = fmaxf(ov.y, 0.f);
    ov.z = fmaxf(ov.z, 0.f); ov.w = fmaxf(ov.w, 0.f);
  }
  st4(out, (size_t)n*256 + c0, ov, of32);
}

// ---------------- query part of classifier ----------------
__global__ void qpart_kernel(const void* __restrict__ query, const void* __restrict__ Wc,
    const void* __restrict__ bc, float* __restrict__ qp, int Q, const int* __restrict__ flags){
  int f32 = flags[0];
  int q = threadIdx.x >> 5, ln = threadIdx.x & 31;
  if (q >= Q) return;
  float s = 0.f;
  for (int j = ln; j < 256; j += 32) s += ld1(query, q*256 + j, f32) * ld1(Wc, j, f32);
  #pragma unroll
  for (int off = 16; off; off >>= 1) s += __shfl_down(s, off, 32);
  if (ln == 0) qp[q] = s + ld1(bc, 0, f32);
}

// ---------------- node scores ----------------
__global__ __launch_bounds__(256) void nscore_kernel(const void* __restrict__ dout,
    const void* __restrict__ Wc, const float* __restrict__ qp, int N, int Q,
    const int* __restrict__ flags){
  int f32 = flags[0];
  int wv = threadIdx.x >> 6, ln = threadIdx.x & 63;
  int n = blockIdx.x * 4 + wv;
  if (n >= N) return;
  float4 e4 = ld4(dout, (size_t)n*256 + ln*4, f32);
  float4 w4 = ld4(Wc, 256 + ln*4, f32);
  float v = e4.x*w4.x + e4.y*w4.y + e4.z*w4.z + e4.w*w4.w;
  #pragma unroll
  for (int off = 32; off; off >>= 1) v += __shfl_down(v, off, 64);
  v = __shfl(v, 0, 64);
  if (ln < Q) st1((void*)dout, (size_t)N*256 + (size_t)ln*N + n, qp[ln] + v, f32);
}

extern "C" void kernel_launch(void* const* d_in, const int* in_sizes, int n_in,
                              void* d_out, int out_size, void* d_ws, size_t ws_size,
                              hipStream_t stream){
  const void* x     = d_in[0];
  const int*  ei    = (const int*)d_in[1];
  const void* query = d_in[2];
  const void* W1    = d_in[3];
  const void* as1   = d_in[4];
  const void* ad1   = d_in[5];
  const void* b1    = d_in[6];
  const void* W2    = d_in[7];
  const void* as2   = d_in[8];
  const void* ad2   = d_in[9];
  const void* b2    = d_in[10];
  const void* Wc    = d_in[11];
  const void* bc    = d_in[12];

  int N = in_sizes[0] / 256;
  int E = in_sizes[1] / 2;
  int Q = in_sizes[2] / 256;
  int Et = E + N;
  int NB = (N + 255) / 256;   // scan blocks (<=1024 for N<=262144)

  char* p = (char*)d_ws;
  auto alloc = [&](size_t bytes)->char*{
    char* r = p; p += (bytes + 255) & ~(size_t)255; return r;
  };
  int*  flags   = (int*) alloc(256);
  u16*  bufA    = (u16*) alloc((size_t)N*256*2);
  u16*  bufB    = (u16*) alloc((size_t)N*256*2);
  float* es     = (float*)alloc((size_t)N*4*4);
  float* ed     = (float*)alloc((size_t)N*4*4);
  int*  deg     = (int*)  alloc((size_t)N*4);
  int*  offs    = (int*)  alloc((size_t)(N+1)*4);
  int*  cursor  = (int*)  alloc((size_t)N*4);
  int*  csr_src = (int*)  alloc((size_t)Et*4);
  int*  bsum    = (int*)  alloc((size_t)(NB+1)*4);
  int*  bpre    = (int*)  alloc((size_t)(NB+1)*4);
  float* qp     = (float*)alloc(64*4);

  const int thr = 256;
  detect_kernel<<<1, 256, 0, stream>>>((const u32*)x, ei, flags);

  hipMemsetAsync(deg, 0, (size_t)N*4, stream);
  count_kernel  <<<(Et + thr-1)/thr, thr, 0, stream>>>(ei, E, N, deg, flags);
  scan1_kernel  <<<NB, 256, 0, stream>>>(deg, offs, bsum, N);
  scan2_kernel  <<<1, 1024, 0, stream>>>(bsum, bpre, NB);
  scan3_kernel  <<<NB, 256, 0, stream>>>(offs, cursor, bpre, N, NB);
  scatter_kernel<<<(Et + thr-1)/thr, thr, 0, stream>>>(ei, E, N, cursor, csr_src, flags);

  dim3 ggrid(4, (N + 127)/128);
  dim3 ngrid((N + 3)/4);
  // ---- layer 1 ----
  gemm_mfma    <<<ggrid, 256, 0, stream>>>(x, W1, bufA, N, 1, flags);
  scores_kernel<<<ngrid, 256, 0, stream>>>(bufA, as1, ad1, es, ed, N, flags);
  agg_kernel   <<<ngrid, 256, 0, stream>>>(bufA, csr_src, offs, es, ed, N, b1, bufB, 1, 0, flags);
  // ---- layer 2 ----
  gemm_mfma    <<<ggrid, 256, 0, stream>>>(bufB, W2, bufA, N, 0, flags);
  scores_kernel<<<ngrid, 256, 0, stream>>>(bufA, as2, ad2, es, ed, N, flags);
  agg_kernel   <<<ngrid, 256, 0, stream>>>(bufA, csr_src, offs, es, ed, N, b2, d_out, 0, 1, flags);
  // ---- classifier head ----
  qpart_kernel <<<1, 256, 0, stream>>>(query, Wc, bc, qp, Q, flags);
  nscore_kernel<<<ngrid, 256, 0, stream>>>(d_out, Wc, qp, N, Q, flags);
}